// Round 1
// baseline (85.477 us; speedup 1.0000x reference)
//
#include <hip/hip_runtime.h>

// Problem constants (B,S,D,R) = (8,512,768,128)
#define NB 8
#define NS 512
#define ND 768
#define NR 128
#define NM (NB * NS)                       // 4096 rows total
#define DIST_ELEMS ((size_t)NB * NS * NS)  // 2097152

typedef short bf16x8 __attribute__((ext_vector_type(8)));  // 8 bf16 (4 VGPRs)
typedef __bf16 bfv8  __attribute__((ext_vector_type(8)));  // native bf16 vec
typedef float f32x4  __attribute__((ext_vector_type(4)));  // MFMA C/D frag

// RNE fp32->bf16 via native __bf16 casts: compiler emits v_cvt_pk_bf16_f32
// pairs (~0.5 VALU/elem vs ~3 for the old add+shift bit-trick). The SAME
// rounding feeds P, the norms, and the Gram MFMA, so d(i,i) stays ~0.
__device__ __forceinline__ unsigned short f2bf(float f) {
  return __builtin_bit_cast(unsigned short, (__bf16)f);
}
__device__ __forceinline__ float bf2f(unsigned short h) {
  return __uint_as_float(((unsigned int)h) << 16);
}
__device__ __forceinline__ bf16x8 pack8(float4 lo, float4 hi) {
  bfv8 v;
  v[0] = (__bf16)lo.x; v[1] = (__bf16)lo.y;
  v[2] = (__bf16)lo.z; v[3] = (__bf16)lo.w;
  v[4] = (__bf16)hi.x; v[5] = (__bf16)hi.y;
  v[6] = (__bf16)hi.z; v[7] = (__bf16)hi.w;
  return __builtin_bit_cast(bf16x8, v);
}

// ---------------------------------------------------------------------------
// Kernel 1: proj GEMM, bf16 MFMA, M-tile 32, KT=128, 6 K-iters.
// grid (128, 4) -- m0-major so the 4 ct-blocks of one m-tile are 128 apart in
// linear id === same XCD (id%8): emb tile is HBM-read once, L2-hit 3x.
//   ct=0/1: P cols 0-63 / 64-127 (projD) -> write P + norm partial nP0/nP1
//   ct=2/3: projP halves                 -> norm partial nD0/nD1
//
// B (proj) has ZERO intra-block sharing: each wave reads only its own 16 rows,
// once. So B skips LDS entirely -- MFMA B-fragments are loaded straight from
// global (786 KB proj is L2-resident after the first toucher) and converted
// in-register. Only A stays in LDS (shared by all 4 waves), double-buffered
// so the loop needs ONE barrier per K-iter instead of two.
// LDS row stride 136 bf16 (68 dw === 4 mod 32): uniform bytes/bank on b128.
// ---------------------------------------------------------------------------
constexpr int KT  = 128;
constexpr int SAS = 136;

__global__ __launch_bounds__(256) void proj_kernel(
    const float* __restrict__ emb,
    const float* __restrict__ projD,
    const float* __restrict__ projP,
    unsigned short* __restrict__ P,       // bf16 bits, 4096x128
    float* __restrict__ nP0, float* __restrict__ nP1,   // dist norm partials
    float* __restrict__ nD0, float* __restrict__ nD1)   // depth partials
{
  __shared__ unsigned short sA[2][32][SAS];   // 2 x 8.7 KB
  __shared__ float sRed[4][32];

  const int tid = threadIdx.x;
  const int m0  = blockIdx.x * 32;
  const int ct  = blockIdx.y;              // 0..3
  const bool isP = (ct < 2);
  const float* proj = (isP ? projD : projP) + (size_t)((ct & 1) * 64) * ND;

  // A staging: 32 rows x 16 octets -> thread t: row t>>3, octets t&7, (t&7)+8
  const int ar = tid >> 3, ao = tid & 7;
  const float* aPtr = emb + (size_t)(m0 + ar) * ND + ao * 8;

  const int lane = tid & 63;
  const int w    = tid >> 6;
  const int ln   = lane & 15;
  const int q    = lane >> 4;

  // per-thread B row base: this thread's MFMA B-fragment source (row 16w+ln,
  // k-offset q*8). Per ks it reads 32 contiguous bytes x4 -> 128 B/row/iter.
  const float* bRow = proj + (size_t)(16 * w + ln) * ND + q * 8;

  float4 a0, a1, a2, a3;
  a0 = *(const float4*)(aPtr);      a1 = *(const float4*)(aPtr + 4);
  a2 = *(const float4*)(aPtr + 64); a3 = *(const float4*)(aPtr + 68);

  f32x4 acc[2] = {};   // 2 row-frags x 16 cols

  // stage K-tile 0 into buffer 0
  *(bf16x8*)(&sA[0][ar][ao * 8])       = pack8(a0, a1);
  *(bf16x8*)(&sA[0][ar][(ao + 8) * 8]) = pack8(a2, a3);
  __syncthreads();

  int p = 0;
  for (int kt = 0; kt < ND; kt += KT) {
    const bool more = (kt + KT < ND);
    if (more) {  // register prefetch of next A K-tile (4 b128 in flight)
      const int o = kt + KT;
      a0 = *(const float4*)(aPtr + o);      a1 = *(const float4*)(aPtr + o + 4);
      a2 = *(const float4*)(aPtr + o + 64); a3 = *(const float4*)(aPtr + o + 68);
    }
    // B fragments straight from global (L2), convert fp32->bf16 in-register
    bf16x8 bq[4];
    #pragma unroll
    for (int ks = 0; ks < 4; ++ks) {
      const float* bp = bRow + kt + ks * 32;
      float4 lo = *(const float4*)bp;
      float4 hi = *(const float4*)(bp + 4);
      bq[ks] = pack8(lo, hi);
    }
    #pragma unroll
    for (int ks = 0; ks < 4; ++ks) {
      #pragma unroll
      for (int i = 0; i < 2; ++i) {
        bf16x8 aq = *(const bf16x8*)(&sA[p][16 * i + ln][ks * 32 + q * 8]);
        acc[i] = __builtin_amdgcn_mfma_f32_16x16x32_bf16(aq, bq[ks], acc[i], 0, 0, 0);
      }
    }
    if (more) {  // stage next tile into the other buffer; one barrier/iter
      *(bf16x8*)(&sA[p ^ 1][ar][ao * 8])       = pack8(a0, a1);
      *(bf16x8*)(&sA[p ^ 1][ar][(ao + 8) * 8]) = pack8(a2, a3);
    }
    __syncthreads();
    p ^= 1;
  }

  // Epilogue. C/D layout: col = lane&15, row = 16i + 4q + r.
  const int colG = (ct & 1) * 64 + 16 * w + ln;
  #pragma unroll
  for (int i = 0; i < 2; ++i)
    #pragma unroll
    for (int r = 0; r < 4; ++r) {
      unsigned short hb = f2bf(acc[i][r]);
      if (isP) P[(size_t)(m0 + 16 * i + 4 * q + r) * NR + colG] = hb;
      float v = bf2f(hb);       // norm from the SAME rounded value
      float s = v * v;
      s += __shfl_xor(s, 1);
      s += __shfl_xor(s, 2);
      s += __shfl_xor(s, 4);
      s += __shfl_xor(s, 8);
      if (ln == 0) sRed[w][16 * i + 4 * q + r] = s;
    }
  __syncthreads();
  if (tid < 32) {
    float* np = (ct == 0) ? nP0 : (ct == 1) ? nP1 : (ct == 2) ? nD0 : nD1;
    np[m0 + tid] = sRed[0][tid] + sRed[1][tid] + sRed[2][tid] + sRed[3][tid];
  }
}

// ---------------------------------------------------------------------------
// Kernel 2: out[b,i,j] = n[i] + n[j] - 2*(Pb Pb^T)[i,j].  LDS-free Gram:
// MFMA fragments straight from global P (16 B/lane, full 64 B line coverage).
// j0==0 blocks additionally combine depth partials -> depths output.
// ---------------------------------------------------------------------------
__global__ __launch_bounds__(256) void dist_kernel(
    const unsigned short* __restrict__ P,
    const float* __restrict__ nP0, const float* __restrict__ nP1,
    const float* __restrict__ nD0, const float* __restrict__ nD1,
    float* __restrict__ out,
    float* __restrict__ depths)
{
  __shared__ float nIs[64], nJs[64];

  const int tid = threadIdx.x;
  const int b  = blockIdx.z;
  const int i0 = blockIdx.y * 64;
  const int j0 = blockIdx.x * 64;
  const unsigned short* Pb = P + (size_t)b * NS * NR;
  const int mB = b * NS;                  // norms indexed by global row

  if (tid < 64) {
    nIs[tid] = nP0[mB + i0 + tid] + nP1[mB + i0 + tid];
  } else if (tid < 128) {
    const int t = tid - 64;
    nJs[t] = nP0[mB + j0 + t] + nP1[mB + j0 + t];
  } else if (blockIdx.x == 0 && tid < 192) {
    const int t = tid - 128;              // depths combine (64 blocks cover all)
    depths[mB + i0 + t] = nD0[mB + i0 + t] + nD1[mB + i0 + t];
  }

  const int lane = tid & 63;
  const int w    = tid >> 6;
  const int ln   = lane & 15;
  const int q    = lane >> 4;

  // preload all fragments for max MLP (20 b128 loads in flight)
  bf16x8 aq[4][4], bq[4];
  #pragma unroll
  for (int ks = 0; ks < 4; ++ks) {
    bq[ks] = *(const bf16x8*)(Pb + (size_t)(j0 + 16 * w + ln) * NR + ks * 32 + q * 8);
    #pragma unroll
    for (int i = 0; i < 4; ++i)
      aq[i][ks] = *(const bf16x8*)(Pb + (size_t)(i0 + 16 * i + ln) * NR + ks * 32 + q * 8);
  }

  f32x4 acc[4] = {};
  #pragma unroll
  for (int ks = 0; ks < 4; ++ks)
    #pragma unroll
    for (int i = 0; i < 4; ++i)
      acc[i] = __builtin_amdgcn_mfma_f32_16x16x32_bf16(aq[i][ks], bq[ks], acc[i], 0, 0, 0);

  __syncthreads();   // norm tile ready (moved after MFMA: loads don't wait)

  const int col = j0 + 16 * w + ln;
  const float nj = nJs[16 * w + ln];
  float* ob = out + (size_t)b * NS * NS;
  #pragma unroll
  for (int i = 0; i < 4; ++i)
    #pragma unroll
    for (int r = 0; r < 4; ++r) {
      const int rloc = 16 * i + 4 * q + r;
      ob[(size_t)(i0 + rloc) * NS + col] = nIs[rloc] + nj - 2.0f * acc[i][r];
    }
}

// ---------------------------------------------------------------------------
extern "C" void kernel_launch(void* const* d_in, const int* in_sizes, int n_in,
                              void* d_out, int out_size, void* d_ws, size_t ws_size,
                              hipStream_t stream) {
  const float* emb   = (const float*)d_in[0];
  const float* projD = (const float*)d_in[1];
  const float* projP = (const float*)d_in[2];
  float* out = (float*)d_out;

  unsigned short* P = (unsigned short*)d_ws;                  // bf16, 1 MB
  float* nP0 = (float*)((char*)d_ws + (size_t)NM * NR * 2);
  float* nP1 = nP0 + NM;
  float* nD0 = nP1 + NM;
  float* nD1 = nD0 + NM;
  float* depths = out + DIST_ELEMS;                           // output [4096]

  proj_kernel<<<dim3(NM / 32, 4), 256, 0, stream>>>(emb, projD, projP, P, nP0, nP1, nD0, nD1);
  dist_kernel<<<dim3(NS / 64, NS / 64, NB), 256, 0, stream>>>(P, nP0, nP1, nD0, nD1, out, depths);
}

// Round 2
// 84.862 us; speedup vs baseline: 1.0073x; 1.0073x over previous
//
#include <hip/hip_runtime.h>

// Problem constants (B,S,D,R) = (8,512,768,128)
#define NB 8
#define NS 512
#define ND 768
#define NR 128
#define NM (NB * NS)                       // 4096 rows total
#define DIST_ELEMS ((size_t)NB * NS * NS)  // 2097152

typedef short bf16x8 __attribute__((ext_vector_type(8)));  // 8 bf16 (4 VGPRs)
typedef __bf16 bfv8  __attribute__((ext_vector_type(8)));  // native bf16 vec
typedef float f32x4  __attribute__((ext_vector_type(4)));  // MFMA C/D frag

// RNE fp32->bf16 via native __bf16 casts: compiler emits v_cvt_pk_bf16_f32
// pairs (~0.5 VALU/elem). The SAME rounding feeds P, the norms, and the Gram
// MFMA, so d(i,i) stays ~0.
__device__ __forceinline__ unsigned short f2bf(float f) {
  return __builtin_bit_cast(unsigned short, (__bf16)f);
}
__device__ __forceinline__ float bf2f(unsigned short h) {
  return __uint_as_float(((unsigned int)h) << 16);
}
__device__ __forceinline__ bf16x8 pack8(float4 lo, float4 hi) {
  bfv8 v;
  v[0] = (__bf16)lo.x; v[1] = (__bf16)lo.y;
  v[2] = (__bf16)lo.z; v[3] = (__bf16)lo.w;
  v[4] = (__bf16)hi.x; v[5] = (__bf16)hi.y;
  v[6] = (__bf16)hi.z; v[7] = (__bf16)hi.w;
  return __builtin_bit_cast(bf16x8, v);
}

// ---------------------------------------------------------------------------
// Kernel 1: proj GEMM, bf16 MFMA, M-tile 32, KT=128, 6 K-iters.
// grid (128, 4) -- m0-major so the 4 ct-blocks of one m-tile are 128 apart in
// linear id === same XCD (id%8): emb tile is HBM-read once, L2-hit 3x.
//   ct=0/1: P cols 0-63 / 64-127 (projD) -> write P + norm partial nP0/nP1
//   ct=2/3: projP halves                 -> norm partial nD0/nD1
//
// B (proj) has ZERO intra-block sharing (each wave consumes only its own 16
// rows, once) -> B skips LDS entirely: MFMA B-fragments come straight from
// global (proj is L2-resident) and are converted in-register. Only A stays
// in LDS (shared by all 4 waves).
//
// Pipeline (the round-1 lesson): BOTH A and B are register-prefetched a full
// K-iteration ahead (Ar/Br double buffers). __syncthreads() would drain
// vmcnt(0) and kill that prefetch (the m97 barrier-drain stall), so the
// barrier is the minimal correct form:
//     s_waitcnt lgkmcnt(0)   -- ds_writes of sA drained
//     s_barrier               -- raw, vmcnt NOT drained -> prefetch survives
//     sched_barrier(0)        -- pin following ds_reads below the barrier
// One barrier per iter, sA double-buffered: stage_t writes sA[t&1]; the
// prior reader of that buffer is MFMA_{t-2}, separated by barrier_{t-1}.
// LDS row stride 136 bf16 (68 dw === 4 mod 32): uniform bytes/bank on b128.
// ---------------------------------------------------------------------------
constexpr int KT  = 128;
constexpr int NKT = ND / KT;   // 6
constexpr int SAS = 136;

__global__ __launch_bounds__(256) void proj_kernel(
    const float* __restrict__ emb,
    const float* __restrict__ projD,
    const float* __restrict__ projP,
    unsigned short* __restrict__ P,       // bf16 bits, 4096x128
    float* __restrict__ nP0, float* __restrict__ nP1,   // dist norm partials
    float* __restrict__ nD0, float* __restrict__ nD1)   // depth partials
{
  __shared__ unsigned short sA[2][32][SAS];   // 2 x 8.7 KB
  __shared__ float sRed[4][32];

  const int tid = threadIdx.x;
  const int m0  = blockIdx.x * 32;
  const int ct  = blockIdx.y;              // 0..3
  const bool isP = (ct < 2);
  const float* proj = (isP ? projD : projP) + (size_t)((ct & 1) * 64) * ND;

  // A staging: 32 rows x 16 octets -> thread t: row t>>3, octets t&7, (t&7)+8
  const int ar = tid >> 3, ao = tid & 7;
  const float* aPtr = emb + (size_t)(m0 + ar) * ND + ao * 8;

  const int lane = tid & 63;
  const int w    = tid >> 6;
  const int ln   = lane & 15;
  const int q    = lane >> 4;

  // per-thread B row base: this thread's MFMA B-fragment source (row 16w+ln,
  // k-offset q*8). Per iter it reads 4x32 contiguous bytes of this row.
  const float* bRow = proj + (size_t)(16 * w + ln) * ND + q * 8;

  // register double-buffers; all indices compile-time (full unroll) -> VGPRs
  float4 Ar[2][4], Br[2][8];
  Ar[0][0] = *(const float4*)(aPtr);      Ar[0][1] = *(const float4*)(aPtr + 4);
  Ar[0][2] = *(const float4*)(aPtr + 64); Ar[0][3] = *(const float4*)(aPtr + 68);
  Br[0][0] = *(const float4*)(bRow);      Br[0][1] = *(const float4*)(bRow + 4);
  Br[0][2] = *(const float4*)(bRow + 32); Br[0][3] = *(const float4*)(bRow + 36);
  Br[0][4] = *(const float4*)(bRow + 64); Br[0][5] = *(const float4*)(bRow + 68);
  Br[0][6] = *(const float4*)(bRow + 96); Br[0][7] = *(const float4*)(bRow + 100);

  f32x4 acc[2] = {};   // 2 row-frags x 16 cols

  #pragma unroll
  for (int t = 0; t < NKT; ++t) {
    const int cur = t & 1;
    // stage current A tile (regs loaded a full iteration ago; first iter's
    // ds_write vmcnt-waits on the prologue loads via compiler tracking)
    *(bf16x8*)(&sA[cur][ar][ao * 8])       = pack8(Ar[cur][0], Ar[cur][1]);
    *(bf16x8*)(&sA[cur][ar][(ao + 8) * 8]) = pack8(Ar[cur][2], Ar[cur][3]);
    // minimal barrier: drain LDS writes only; vmcnt prefetch stays in flight
    asm volatile("s_waitcnt lgkmcnt(0)" ::: "memory");
    __builtin_amdgcn_s_barrier();
    __builtin_amdgcn_sched_barrier(0);
    // issue next tile's global loads NOW (consumed next iteration)
    if (t + 1 < NKT) {
      const int o = (t + 1) * KT;
      const int nxt = cur ^ 1;
      Ar[nxt][0] = *(const float4*)(aPtr + o);
      Ar[nxt][1] = *(const float4*)(aPtr + o + 4);
      Ar[nxt][2] = *(const float4*)(aPtr + o + 64);
      Ar[nxt][3] = *(const float4*)(aPtr + o + 68);
      Br[nxt][0] = *(const float4*)(bRow + o);
      Br[nxt][1] = *(const float4*)(bRow + o + 4);
      Br[nxt][2] = *(const float4*)(bRow + o + 32);
      Br[nxt][3] = *(const float4*)(bRow + o + 36);
      Br[nxt][4] = *(const float4*)(bRow + o + 64);
      Br[nxt][5] = *(const float4*)(bRow + o + 68);
      Br[nxt][6] = *(const float4*)(bRow + o + 96);
      Br[nxt][7] = *(const float4*)(bRow + o + 100);
    }
    // B fragments from current regs (resident since last iteration)
    bf16x8 bq[4];
    #pragma unroll
    for (int ks = 0; ks < 4; ++ks)
      bq[ks] = pack8(Br[cur][2 * ks], Br[cur][2 * ks + 1]);
    #pragma unroll
    for (int ks = 0; ks < 4; ++ks) {
      #pragma unroll
      for (int i = 0; i < 2; ++i) {
        bf16x8 aq = *(const bf16x8*)(&sA[cur][16 * i + ln][ks * 32 + q * 8]);
        acc[i] = __builtin_amdgcn_mfma_f32_16x16x32_bf16(aq, bq[ks], acc[i], 0, 0, 0);
      }
    }
    // no trailing barrier: stage_{t+1} targets the OTHER sA buffer; the
    // overwrite hazard vs MFMA_{t-1} is covered by this iteration's barrier.
  }

  // Epilogue. C/D layout: col = lane&15, row = 16i + 4q + r.
  const int colG = (ct & 1) * 64 + 16 * w + ln;
  #pragma unroll
  for (int i = 0; i < 2; ++i)
    #pragma unroll
    for (int r = 0; r < 4; ++r) {
      unsigned short hb = f2bf(acc[i][r]);
      if (isP) P[(size_t)(m0 + 16 * i + 4 * q + r) * NR + colG] = hb;
      float v = bf2f(hb);       // norm from the SAME rounded value
      float s = v * v;
      s += __shfl_xor(s, 1);
      s += __shfl_xor(s, 2);
      s += __shfl_xor(s, 4);
      s += __shfl_xor(s, 8);
      if (ln == 0) sRed[w][16 * i + 4 * q + r] = s;
    }
  __syncthreads();
  if (tid < 32) {
    float* np = (ct == 0) ? nP0 : (ct == 1) ? nP1 : (ct == 2) ? nD0 : nD1;
    np[m0 + tid] = sRed[0][tid] + sRed[1][tid] + sRed[2][tid] + sRed[3][tid];
  }
}

// ---------------------------------------------------------------------------
// Kernel 2: out[b,i,j] = n[i] + n[j] - 2*(Pb Pb^T)[i,j].  LDS-free Gram:
// MFMA fragments straight from global P (16 B/lane, full 64 B line coverage).
// j0==0 blocks additionally combine depth partials -> depths output.
// ---------------------------------------------------------------------------
__global__ __launch_bounds__(256) void dist_kernel(
    const unsigned short* __restrict__ P,
    const float* __restrict__ nP0, const float* __restrict__ nP1,
    const float* __restrict__ nD0, const float* __restrict__ nD1,
    float* __restrict__ out,
    float* __restrict__ depths)
{
  __shared__ float nIs[64], nJs[64];

  const int tid = threadIdx.x;
  const int b  = blockIdx.z;
  const int i0 = blockIdx.y * 64;
  const int j0 = blockIdx.x * 64;
  const unsigned short* Pb = P + (size_t)b * NS * NR;
  const int mB = b * NS;                  // norms indexed by global row

  if (tid < 64) {
    nIs[tid] = nP0[mB + i0 + tid] + nP1[mB + i0 + tid];
  } else if (tid < 128) {
    const int t = tid - 64;
    nJs[t] = nP0[mB + j0 + t] + nP1[mB + j0 + t];
  } else if (blockIdx.x == 0 && tid < 192) {
    const int t = tid - 128;              // depths combine (64 blocks cover all)
    depths[mB + i0 + t] = nD0[mB + i0 + t] + nD1[mB + i0 + t];
  }

  const int lane = tid & 63;
  const int w    = tid >> 6;
  const int ln   = lane & 15;
  const int q    = lane >> 4;

  // preload all fragments for max MLP (20 b128 loads in flight)
  bf16x8 aq[4][4], bq[4];
  #pragma unroll
  for (int ks = 0; ks < 4; ++ks) {
    bq[ks] = *(const bf16x8*)(Pb + (size_t)(j0 + 16 * w + ln) * NR + ks * 32 + q * 8);
    #pragma unroll
    for (int i = 0; i < 4; ++i)
      aq[i][ks] = *(const bf16x8*)(Pb + (size_t)(i0 + 16 * i + ln) * NR + ks * 32 + q * 8);
  }

  f32x4 acc[4] = {};
  #pragma unroll
  for (int ks = 0; ks < 4; ++ks)
    #pragma unroll
    for (int i = 0; i < 4; ++i)
      acc[i] = __builtin_amdgcn_mfma_f32_16x16x32_bf16(aq[i][ks], bq[ks], acc[i], 0, 0, 0);

  __syncthreads();   // norm tile ready (after MFMA: loads don't wait on it)

  const int col = j0 + 16 * w + ln;
  const float nj = nJs[16 * w + ln];
  float* ob = out + (size_t)b * NS * NS;
  #pragma unroll
  for (int i = 0; i < 4; ++i)
    #pragma unroll
    for (int r = 0; r < 4; ++r) {
      const int rloc = 16 * i + 4 * q + r;
      ob[(size_t)(i0 + rloc) * NS + col] = nIs[rloc] + nj - 2.0f * acc[i][r];
    }
}

// ---------------------------------------------------------------------------
extern "C" void kernel_launch(void* const* d_in, const int* in_sizes, int n_in,
                              void* d_out, int out_size, void* d_ws, size_t ws_size,
                              hipStream_t stream) {
  const float* emb   = (const float*)d_in[0];
  const float* projD = (const float*)d_in[1];
  const float* projP = (const float*)d_in[2];
  float* out = (float*)d_out;

  unsigned short* P = (unsigned short*)d_ws;                  // bf16, 1 MB
  float* nP0 = (float*)((char*)d_ws + (size_t)NM * NR * 2);
  float* nP1 = nP0 + NM;
  float* nD0 = nP1 + NM;
  float* nD1 = nD0 + NM;
  float* depths = out + DIST_ELEMS;                           // output [4096]

  proj_kernel<<<dim3(NM / 32, 4), 256, 0, stream>>>(emb, projD, projP, P, nP0, nP1, nD0, nD1);
  dist_kernel<<<dim3(NS / 64, NS / 64, NB), 256, 0, stream>>>(P, nP0, nP1, nD0, nD1, out, depths);
}

// Round 3
// 78.850 us; speedup vs baseline: 1.0840x; 1.0762x over previous
//
#include <hip/hip_runtime.h>

// Problem constants (B,S,D,R) = (8,512,768,128)
#define NB 8
#define NS 512
#define ND 768
#define NR 128
#define NM (NB * NS)                       // 4096 rows total
#define DIST_ELEMS ((size_t)NB * NS * NS)  // 2097152

typedef short bf16x8 __attribute__((ext_vector_type(8)));  // 8 bf16 (4 VGPRs)
typedef float f32x4  __attribute__((ext_vector_type(4)));  // MFMA C/D frag

// round-half-up fp32->bf16: 2 VALU ops; the SAME rounding feeds P, the norms,
// and the Gram MFMA, so d(i,i) stays ~0.
__device__ __forceinline__ unsigned short f2bf(float f) {
  return (unsigned short)((__float_as_uint(f) + 0x8000u) >> 16);
}
__device__ __forceinline__ float bf2f(unsigned short h) {
  return __uint_as_float(((unsigned int)h) << 16);
}
__device__ __forceinline__ bf16x8 pack8(float4 lo, float4 hi) {
  bf16x8 p;
  p[0] = (short)f2bf(lo.x); p[1] = (short)f2bf(lo.y);
  p[2] = (short)f2bf(lo.z); p[3] = (short)f2bf(lo.w);
  p[4] = (short)f2bf(hi.x); p[5] = (short)f2bf(hi.y);
  p[6] = (short)f2bf(hi.z); p[7] = (short)f2bf(hi.w);
  return p;
}

// ---------------------------------------------------------------------------
// Kernel 1: proj GEMM, bf16 MFMA, M-tile 32, KT=128 (6 barrier iterations).
// grid (128, 4) -- m0-major so the 4 ct-blocks of one m-tile are 128 apart in
// linear id === same XCD (id%8): emb tile is HBM-read once, L2-hit 3x.
//   ct=0/1: P cols 0-63 / 64-127 (projD) -> write P + norm partial nP0/nP1
//   ct=2/3: projP halves                 -> norm partial nD0/nD1
// LDS row stride 136 bf16 (68 dw === 4 mod 32): b128 frag reads AND staging
// writes have uniform bytes/bank (the b128 bank floor).
//
// NOTE (session journal): two attempted "improvements" regressed ~6 us and
// were reverted -- (a) loading B-fragments straight from global/L2 instead
// of LDS-staging (16-row-scattered b128s, half-line coverage, 2x L2 line
// requests), (b) RNE __bf16 casts for the pack (longer lowering than the
// 2-op bit-trick). This file is the verified-fastest structure; keep the
// dense coalesced staging and the bit-trick pack.
// ---------------------------------------------------------------------------
constexpr int KT  = 128;
constexpr int SAS = 136;

__global__ __launch_bounds__(256) void proj_kernel(
    const float* __restrict__ emb,
    const float* __restrict__ projD,
    const float* __restrict__ projP,
    unsigned short* __restrict__ P,       // bf16 bits, 4096x128
    float* __restrict__ nP0, float* __restrict__ nP1,   // dist norm partials
    float* __restrict__ nD0, float* __restrict__ nD1)   // depth partials
{
  __shared__ unsigned short sA[32][SAS];   // 8.7 KB
  __shared__ unsigned short sB[64][SAS];   // 17.4 KB
  __shared__ float sRed[4][32];

  const int tid = threadIdx.x;
  const int m0  = blockIdx.x * 32;
  const int ct  = blockIdx.y;              // 0..3
  const bool isP = (ct < 2);
  const float* proj = (isP ? projD : projP) + (size_t)((ct & 1) * 64) * ND;

  // A staging: 32 rows x 16 octets -> thread t: row t>>3, octets t&7, (t&7)+8
  const int ar = tid >> 3, ao = tid & 7;
  const float* aPtr = emb + (size_t)(m0 + ar) * ND + ao * 8;
  // B staging: 64 rows x 16 octets -> thread t: row t>>2, octets t&3,+4,+8,+12
  const int br = tid >> 2, bo = tid & 3;
  const float* bPtr = proj + (size_t)br * ND + bo * 8;

  float4 a0, a1, a2, a3;
  float4 c0, c1, c2, c3, c4, c5, c6, c7;
  a0 = *(const float4*)(aPtr);      a1 = *(const float4*)(aPtr + 4);
  a2 = *(const float4*)(aPtr + 64); a3 = *(const float4*)(aPtr + 68);
  c0 = *(const float4*)(bPtr);      c1 = *(const float4*)(bPtr + 4);
  c2 = *(const float4*)(bPtr + 32); c3 = *(const float4*)(bPtr + 36);
  c4 = *(const float4*)(bPtr + 64); c5 = *(const float4*)(bPtr + 68);
  c6 = *(const float4*)(bPtr + 96); c7 = *(const float4*)(bPtr + 100);

  const int lane = tid & 63;
  const int w    = tid >> 6;
  const int ln   = lane & 15;
  const int q    = lane >> 4;

  f32x4 acc[2] = {};   // 2 row-frags x 16 cols

  for (int kt = 0; kt < ND; kt += KT) {
    *(bf16x8*)(&sA[ar][ao * 8])        = pack8(a0, a1);
    *(bf16x8*)(&sA[ar][(ao + 8) * 8])  = pack8(a2, a3);
    *(bf16x8*)(&sB[br][bo * 8])        = pack8(c0, c1);
    *(bf16x8*)(&sB[br][(bo + 4) * 8])  = pack8(c2, c3);
    *(bf16x8*)(&sB[br][(bo + 8) * 8])  = pack8(c4, c5);
    *(bf16x8*)(&sB[br][(bo + 12) * 8]) = pack8(c6, c7);
    __syncthreads();
    if (kt + KT < ND) {  // register prefetch of next K-tile (12 b128 in flight)
      const int o = kt + KT;
      a0 = *(const float4*)(aPtr + o);      a1 = *(const float4*)(aPtr + o + 4);
      a2 = *(const float4*)(aPtr + o + 64); a3 = *(const float4*)(aPtr + o + 68);
      c0 = *(const float4*)(bPtr + o);      c1 = *(const float4*)(bPtr + o + 4);
      c2 = *(const float4*)(bPtr + o + 32); c3 = *(const float4*)(bPtr + o + 36);
      c4 = *(const float4*)(bPtr + o + 64); c5 = *(const float4*)(bPtr + o + 68);
      c6 = *(const float4*)(bPtr + o + 96); c7 = *(const float4*)(bPtr + o + 100);
    }
    #pragma unroll
    for (int ks = 0; ks < 4; ++ks) {
      bf16x8 bq = *(const bf16x8*)(&sB[16 * w + ln][ks * 32 + q * 8]);
      #pragma unroll
      for (int i = 0; i < 2; ++i) {
        bf16x8 aq = *(const bf16x8*)(&sA[16 * i + ln][ks * 32 + q * 8]);
        acc[i] = __builtin_amdgcn_mfma_f32_16x16x32_bf16(aq, bq, acc[i], 0, 0, 0);
      }
    }
    __syncthreads();
  }

  // Epilogue. C/D layout: col = lane&15, row = 16i + 4q + r.
  const int colG = (ct & 1) * 64 + 16 * w + ln;
  #pragma unroll
  for (int i = 0; i < 2; ++i)
    #pragma unroll
    for (int r = 0; r < 4; ++r) {
      unsigned short hb = f2bf(acc[i][r]);
      if (isP) P[(size_t)(m0 + 16 * i + 4 * q + r) * NR + colG] = hb;
      float v = bf2f(hb);       // norm from the SAME rounded value
      float s = v * v;
      s += __shfl_xor(s, 1);
      s += __shfl_xor(s, 2);
      s += __shfl_xor(s, 4);
      s += __shfl_xor(s, 8);
      if (ln == 0) sRed[w][16 * i + 4 * q + r] = s;
    }
  __syncthreads();
  if (tid < 32) {
    float* np = (ct == 0) ? nP0 : (ct == 1) ? nP1 : (ct == 2) ? nD0 : nD1;
    np[m0 + tid] = sRed[0][tid] + sRed[1][tid] + sRed[2][tid] + sRed[3][tid];
  }
}

// ---------------------------------------------------------------------------
// Kernel 2: out[b,i,j] = n[i] + n[j] - 2*(Pb Pb^T)[i,j].  LDS-free Gram:
// MFMA fragments straight from global P (16 B/lane, full 64 B line coverage).
// j0==0 blocks additionally combine depth partials -> depths output.
// ---------------------------------------------------------------------------
__global__ __launch_bounds__(256) void dist_kernel(
    const unsigned short* __restrict__ P,
    const float* __restrict__ nP0, const float* __restrict__ nP1,
    const float* __restrict__ nD0, const float* __restrict__ nD1,
    float* __restrict__ out,
    float* __restrict__ depths)
{
  __shared__ float nIs[64], nJs[64];

  const int tid = threadIdx.x;
  const int b  = blockIdx.z;
  const int i0 = blockIdx.y * 64;
  const int j0 = blockIdx.x * 64;
  const unsigned short* Pb = P + (size_t)b * NS * NR;
  const int mB = b * NS;                  // norms indexed by global row

  if (tid < 64) {
    nIs[tid] = nP0[mB + i0 + tid] + nP1[mB + i0 + tid];
  } else if (tid < 128) {
    const int t = tid - 64;
    nJs[t] = nP0[mB + j0 + t] + nP1[mB + j0 + t];
  } else if (blockIdx.x == 0 && tid < 192) {
    const int t = tid - 128;              // depths combine (64 blocks cover all)
    depths[mB + i0 + t] = nD0[mB + i0 + t] + nD1[mB + i0 + t];
  }

  const int lane = tid & 63;
  const int w    = tid >> 6;
  const int ln   = lane & 15;
  const int q    = lane >> 4;

  // preload all fragments for max MLP (20 b128 loads in flight)
  bf16x8 aq[4][4], bq[4];
  #pragma unroll
  for (int ks = 0; ks < 4; ++ks) {
    bq[ks] = *(const bf16x8*)(Pb + (size_t)(j0 + 16 * w + ln) * NR + ks * 32 + q * 8);
    #pragma unroll
    for (int i = 0; i < 4; ++i)
      aq[i][ks] = *(const bf16x8*)(Pb + (size_t)(i0 + 16 * i + ln) * NR + ks * 32 + q * 8);
  }
  __syncthreads();   // norm tile ready

  f32x4 acc[4] = {};
  #pragma unroll
  for (int ks = 0; ks < 4; ++ks)
    #pragma unroll
    for (int i = 0; i < 4; ++i)
      acc[i] = __builtin_amdgcn_mfma_f32_16x16x32_bf16(aq[i][ks], bq[ks], acc[i], 0, 0, 0);

  const int col = j0 + 16 * w + ln;
  const float nj = nJs[16 * w + ln];
  float* ob = out + (size_t)b * NS * NS;
  #pragma unroll
  for (int i = 0; i < 4; ++i)
    #pragma unroll
    for (int r = 0; r < 4; ++r) {
      const int rloc = 16 * i + 4 * q + r;
      ob[(size_t)(i0 + rloc) * NS + col] = nIs[rloc] + nj - 2.0f * acc[i][r];
    }
}

// ---------------------------------------------------------------------------
extern "C" void kernel_launch(void* const* d_in, const int* in_sizes, int n_in,
                              void* d_out, int out_size, void* d_ws, size_t ws_size,
                              hipStream_t stream) {
  const float* emb   = (const float*)d_in[0];
  const float* projD = (const float*)d_in[1];
  const float* projP = (const float*)d_in[2];
  float* out = (float*)d_out;

  unsigned short* P = (unsigned short*)d_ws;                  // bf16, 1 MB
  float* nP0 = (float*)((char*)d_ws + (size_t)NM * NR * 2);
  float* nP1 = nP0 + NM;
  float* nD0 = nP1 + NM;
  float* nD1 = nD0 + NM;
  float* depths = out + DIST_ELEMS;                           // output [4096]

  proj_kernel<<<dim3(NM / 32, 4), 256, 0, stream>>>(emb, projD, projP, P, nP0, nP1, nD0, nD1);
  dist_kernel<<<dim3(NS / 64, NS / 64, NB), 256, 0, stream>>>(P, nP0, nP1, nD0, nD1, out, depths);
}